// Round 4
// baseline (133.499 us; speedup 1.0000x reference)
//
#include <hip/hip_runtime.h>
#include <hip/hip_bf16.h>

typedef __attribute__((ext_vector_type(8))) short short8;
typedef __attribute__((ext_vector_type(4))) float f32x4;

#define ALPHA 0.2f
#define NEG_INF -9e15f
#define OUT_ROWS 126
#define NTILES 521            // ceil(65536/126)
#define NB 4
#define NN 65536
#define TOT (NTILES * NB)     // 2084
#define GRID 512              // persistent: 2 blocks/CU

__device__ __forceinline__ short fb(float x) {
    __hip_bfloat16 b = __float2bfloat16(x);
    return __builtin_bit_cast(short, b);
}

// ---- prep: W -> bf16 B-fragment table; [Wa1 Wa2 0..] -> B2 fragment table ----
__global__ __launch_bounds__(256) void prep_w(const float* __restrict__ W,
                                              const float* __restrict__ a,
                                              unsigned short* __restrict__ ws) {
    const int t = threadIdx.x;
    if (blockIdx.x < 8) {
        int q = blockIdx.x * 256 + t;
        int lane = q & 63, fi = q >> 6;
        int ni = fi & 3, kk = (fi >> 2) & 3, wcg = fi >> 4;
        int n = wcg * 64 + ni * 16 + (lane & 15);
        int k0 = kk * 32 + ((lane >> 4) & 3) * 8;
        short8 o;
        #pragma unroll
        for (int j = 0; j < 8; ++j) o[j] = fb(W[(k0 + j) * 128 + n]);
        *(short8*)(ws + (size_t)q * 8) = o;
    } else {
        __shared__ float wa[2][128];
        {
            int k = t >> 1, sel = t & 1;
            const f32x4* wr4 = (const f32x4*)(W + k * 128);
            const f32x4* av4 = (const f32x4*)(a + sel * 128);
            float s = 0.f;
            #pragma unroll
            for (int c4 = 0; c4 < 32; ++c4) {
                f32x4 wv = wr4[c4], av = av4[c4];
                s += wv[0]*av[0] + wv[1]*av[1] + wv[2]*av[2] + wv[3]*av[3];
            }
            wa[sel][k] = s;
        }
        __syncthreads();
        {
            int lane = t & 63, kk = t >> 6;
            int l15 = lane & 15, lg = (lane >> 4) & 3;
            int k0 = kk * 32 + lg * 8;
            short8 o;
            #pragma unroll
            for (int j = 0; j < 8; ++j) o[j] = fb((l15 < 2) ? wa[l15][k0 + j] : 0.f);
            *(short8*)(ws + 16384 + (size_t)t * 8) = o;
        }
    }
}

// Persistent pipelined kernel: each block loops tiles bid, bid+512, ...
// Per tile: [issue stage loads i+1] -> GEMM(buf[cur]) -> wh/bd writes ->
// cvt+ds_write stage i+1 -> ONE barrier -> in-register combine + stores.
__global__ __launch_bounds__(256, 2)
void gat_fused(const float* __restrict__ h, const int* __restrict__ opm,
               const unsigned short* __restrict__ ws, float* __restrict__ out) {
    __shared__ __align__(16) char bufs[2][32768];   // bf16 h tiles, swizzled
    __shared__ float wh1s[2][128];
    __shared__ float wh2s[2][136];                  // +4 front pad (index 4+row)
    __shared__ float bds[2][2][128];                // band-edge rows 63 / 64

    const int t = threadIdx.x;
    const int lane = t & 63;
    const int wave = t >> 6;
    const int l15 = lane & 15;
    const int lg = (lane >> 4) & 3;
    const int wr = (wave >> 1) << 6;   // row band: 0 or 64
    const int wcg = wave & 1;
    const int wc = wcg << 6;           // col band: 0 or 64

    // ---- hoist B fragments once per block (removes in-loop global loads,
    //      so stage loads are the only vmcnt entries inside the loop) ----
    short8 bfr[4][4];   // [kk][ni]
    short8 bfr2[4];     // [kk]  (Wa1|Wa2 column, used by wcg==0 waves)
    {
        const short8* wsv  = (const short8*)ws;
        const short8* wsv2 = (const short8*)(ws + 16384);
        #pragma unroll
        for (int kk = 0; kk < 4; ++kk) {
            #pragma unroll
            for (int ni = 0; ni < 4; ++ni)
                bfr[kk][ni] = wsv[((((wcg << 2) + kk) << 2) + ni) * 64 + lane];
            bfr2[kk] = wsv2[(kk << 6) + lane];
        }
    }

    int ti = blockIdx.x;

    // ---- prologue: stage first tile into bufs[0] ----
    {
        int b = ti / NTILES;
        int tile = ti - b * NTILES;
        int base = tile * OUT_ROWS - 1;
        const float* hB = h + (size_t)b * NN * 128;
        f32x4 sreg[16];
        #pragma unroll
        for (int i = 0; i < 16; ++i) {
            int rl = (wave << 5) + (i << 1) + (lane >> 5);
            int g = base + rl;
            if (g < 0) g += NN; else if (g >= NN) g -= NN;
            sreg[i] = *(const f32x4*)(hB + (size_t)g * 128 + ((lane & 31) << 2));
        }
        #pragma unroll
        for (int i = 0; i < 16; ++i) {
            int rl = (wave << 5) + (i << 1) + (lane >> 5);
            ushort4 p4;
            p4.x = (unsigned short)fb(sreg[i][0]);
            p4.y = (unsigned short)fb(sreg[i][1]);
            p4.z = (unsigned short)fb(sreg[i][2]);
            p4.w = (unsigned short)fb(sreg[i][3]);
            *(ushort4*)(&bufs[0][rl * 256 + ((((lane & 31) << 3)) ^ ((rl & 7) << 4))]) = p4;
        }
    }
    __syncthreads();

    int cur = 0;
    for (; ti < TOT; ti += GRID) {
        const int b = ti / NTILES;
        const int tile = ti - b * NTILES;
        const int row_start = tile * OUT_ROWS;
        const int base = row_start - 1;
        const int out_rows = min(OUT_ROWS, NN - row_start);
        float* outB = out + (size_t)b * NN * 128;
        const int* opmB = opm + (size_t)b * NN * 3;

        // ---- issue stage loads for next tile (fire-and-forget) ----
        const int tn = ti + GRID;
        const bool has_next = tn < TOT;
        f32x4 sreg[16];
        if (has_next) {
            int b2 = tn / NTILES;
            int tile2 = tn - b2 * NTILES;
            int base2 = tile2 * OUT_ROWS - 1;
            const float* hB2 = h + (size_t)b2 * NN * 128;
            #pragma unroll
            for (int i = 0; i < 16; ++i) {
                int rl = (wave << 5) + (i << 1) + (lane >> 5);
                int g = base2 + rl;
                if (g < 0) g += NN; else if (g >= NN) g -= NN;
                sreg[i] = *(const f32x4*)(hB2 + (size_t)g * 128 + ((lane & 31) << 2));
            }
        }

        // ---- GEMM on bufs[cur] ----
        f32x4 acc[4][4];
        f32x4 acc2[4];
        #pragma unroll
        for (int mi = 0; mi < 4; ++mi) {
            acc2[mi] = (f32x4){0.f, 0.f, 0.f, 0.f};
            #pragma unroll
            for (int ni = 0; ni < 4; ++ni)
                acc[mi][ni] = (f32x4){0.f, 0.f, 0.f, 0.f};
        }
        #pragma unroll
        for (int kk = 0; kk < 4; ++kk) {
            int kb = (kk << 6) + (lg << 4);
            short8 af[4];
            #pragma unroll
            for (int mi = 0; mi < 4; ++mi) {
                int m = wr + (mi << 4) + l15;
                af[mi] = *(const short8*)(&bufs[cur][m * 256 + (kb ^ ((m & 7) << 4))]);
            }
            #pragma unroll
            for (int mi = 0; mi < 4; ++mi)
                #pragma unroll
                for (int ni = 0; ni < 4; ++ni)
                    acc[mi][ni] = __builtin_amdgcn_mfma_f32_16x16x32_bf16(
                        af[mi], bfr[kk][ni], acc[mi][ni], 0, 0, 0);
            if (wcg == 0) {
                #pragma unroll
                for (int mi = 0; mi < 4; ++mi)
                    acc2[mi] = __builtin_amdgcn_mfma_f32_16x16x32_bf16(
                        af[mi], bfr2[kk], acc2[mi], 0, 0, 0);
            }
        }

        const int p = cur;
        // ---- wh1/wh2 (per-row scalars) and band-edge rows to LDS ----
        if (wcg == 0 && l15 < 2) {
            float* dst = (l15 == 0) ? wh1s[p] : (wh2s[p] + 4);
            #pragma unroll
            for (int mi = 0; mi < 4; ++mi)
                #pragma unroll
                for (int j = 0; j < 4; ++j)
                    dst[wr + (mi << 4) + (lg << 2) + j] = acc2[mi][j];
        }
        if (wr == 0) {
            if (lg == 3) {            // row 63 = (mi=3, j=3) at lanes 48..63
                #pragma unroll
                for (int ni = 0; ni < 4; ++ni)
                    bds[p][0][wc + (ni << 4) + l15] = acc[3][ni][3];
            }
        } else {
            if (lg == 0) {            // row 64 = (mi=0, j=0) at lanes 0..15
                #pragma unroll
                for (int ni = 0; ni < 4; ++ni)
                    bds[p][1][wc + (ni << 4) + l15] = acc[0][ni][0];
            }
        }

        // ---- write staged next tile (bf16, swizzled) ----
        if (has_next) {
            #pragma unroll
            for (int i = 0; i < 16; ++i) {
                int rl = (wave << 5) + (i << 1) + (lane >> 5);
                ushort4 p4;
                p4.x = (unsigned short)fb(sreg[i][0]);
                p4.y = (unsigned short)fb(sreg[i][1]);
                p4.z = (unsigned short)fb(sreg[i][2]);
                p4.w = (unsigned short)fb(sreg[i][3]);
                *(ushort4*)(&bufs[cur ^ 1][rl * 256 + ((((lane & 31) << 3)) ^ ((rl & 7) << 4))]) = p4;
            }
        }
        __syncthreads();   // the ONLY barrier per tile

        // ---- neighbor rows via in-wave shuffles ----
        float S[4][4], P[4][4];
        const int ln_n = (lane + 16) & 63;
        const int ln_p = (lane + 48) & 63;
        #pragma unroll
        for (int mi = 0; mi < 4; ++mi)
            #pragma unroll
            for (int ni = 0; ni < 4; ++ni) {
                S[mi][ni] = __shfl(acc[mi][ni][0], ln_n);
                P[mi][ni] = __shfl(acc[mi][ni][3], ln_p);
            }
        float bd0v[4], bd1v[4];
        #pragma unroll
        for (int ni = 0; ni < 4; ++ni) {
            bd0v[ni] = bds[p][0][wc + (ni << 4) + l15];
            bd1v[ni] = bds[p][1][wc + (ni << 4) + l15];
        }

        // ---- per-lane attention + combine + store ----
        #pragma unroll
        for (int mi = 0; mi < 4; ++mi) {
            int r0 = wr + (mi << 4) + (lg << 2);
            f32x4 w1v = *(const f32x4*)(wh1s[p] + r0);       // wh1[r0..r0+3]
            f32x4 w2a = *(const f32x4*)(wh2s[p] + r0);       // wh2[r0-4..r0-1]
            f32x4 w2b = *(const f32x4*)(wh2s[p] + 4 + r0);   // wh2[r0..r0+3]
            f32x4 w2c = *(const f32x4*)(wh2s[p] + 8 + r0);   // wh2[r0+4..r0+7]
            float av[4][3];
            #pragma unroll
            for (int j = 0; j < 4; ++j) {
                int r = r0 + j;
                int g = base + r;
                int gc = g < 0 ? 0 : (g >= NN ? NN - 1 : g);
                const int* mrow = opmB + (size_t)gc * 3;
                int mk0 = mrow[0], mk1 = mrow[1], mk2 = mrow[2];
                float wprev = (j == 0) ? w2a[3] : w2b[j - 1];
                float wnext = (j == 3) ? w2c[0] : w2b[j + 1];
                float w1 = w1v[j];
                float e0 = w1 + wprev, e1 = w1 + w2b[j], e2 = w1 + wnext;
                e0 = e0 > 0.f ? e0 : ALPHA * e0;
                e1 = e1 > 0.f ? e1 : ALPHA * e1;
                e2 = e2 > 0.f ? e2 : ALPHA * e2;
                if (mk0 > 0) e0 = NEG_INF;
                if (mk1 > 0) e1 = NEG_INF;
                if (mk2 > 0) e2 = NEG_INF;
                float m = fmaxf(e0, fmaxf(e1, e2));
                float x0 = __expf(e0 - m), x1 = __expf(e1 - m), x2 = __expf(e2 - m);
                float inv = 1.f / (x0 + x1 + x2);
                av[j][0] = x0 * inv; av[j][1] = x1 * inv; av[j][2] = x2 * inv;
            }
            #pragma unroll
            for (int ni = 0; ni < 4; ++ni) {
                float pv0 = (lg > 0) ? P[mi][ni] : ((mi > 0) ? P[mi - 1][ni] : bd0v[ni]);
                float nx3 = (lg < 3) ? S[mi][ni] : ((mi < 3) ? S[mi + 1][ni] : bd1v[ni]);
                int col = wc + (ni << 4) + l15;
                #pragma unroll
                for (int j = 0; j < 4; ++j) {
                    int r = r0 + j;
                    float pv = (j == 0) ? pv0 : acc[mi][ni][j - 1];
                    float nx = (j == 3) ? nx3 : acc[mi][ni][j + 1];
                    float o = av[j][0] * pv + av[j][1] * acc[mi][ni][j] + av[j][2] * nx;
                    if (r >= 1 && r <= out_rows)
                        outB[(size_t)(base + r) * 128 + col] = o;
                }
            }
        }
        cur ^= 1;
    }
}

extern "C" void kernel_launch(void* const* d_in, const int* in_sizes, int n_in,
                              void* d_out, int out_size, void* d_ws, size_t ws_size,
                              hipStream_t stream) {
    const float* h   = (const float*)d_in[0];
    const int*   opm = (const int*)d_in[1];
    const float* W   = (const float*)d_in[2];
    const float* a   = (const float*)d_in[3];
    float* out = (float*)d_out;
    unsigned short* ws = (unsigned short*)d_ws;
    prep_w<<<9, 256, 0, stream>>>(W, a, ws);
    gat_fused<<<GRID, 256, 0, stream>>>(h, opm, ws, out);
}